// Round 10
// baseline (215.283 us; speedup 1.0000x reference)
//
#include <hip/hip_runtime.h>
#include <hip/hip_bf16.h>
#include <stdint.h>

#define IN_F   4096
#define OUT_F  4096
#define M_ROWS 2048
#define NG     32
#define GRP    128

typedef int   v4i  __attribute__((ext_vector_type(4)));
typedef float f32x4 __attribute__((ext_vector_type(4)));

typedef const void __attribute__((address_space(1))) cv_g;
typedef void       __attribute__((address_space(3))) v_l;

__device__ __forceinline__ void async16(const void* g, void* l) {
  // global -> LDS DMA, 16B/lane; LDS dest = wave-uniform base + lane*16.
  __builtin_amdgcn_global_load_lds((cv_g*)g, (v_l*)l, 16, 0, 0);
}

// perm dtype flag (fallback path only): 1 if int64, 0 if int32.
__device__ int g_perm_is64;

__global__ void decode_flag(const void* __restrict__ perm_raw) {
  if (threadIdx.x == 0 && blockIdx.x == 0) {
    const int* w = (const int*)perm_raw;
    int ok = 1;
    for (int j = 0; j < 32; ++j) {
      int lo = w[2 * j], hi = w[2 * j + 1];
      if (hi != 0 || lo < 0 || lo >= IN_F) { ok = 0; break; }
    }
    g_perm_is64 = ok;
  }
}

// Fused preprocessing, R17 edition (kept: -12us verified). x-path stages
// perm coalesced into an 8KB ushort LDS table once per block instead of
// 128B-stride global re-reads. w-path unchanged.
__global__ __launch_bounds__(256) void prep(const float* __restrict__ x,
                                            const int* __restrict__ w_q,
                                            const void* __restrict__ perm_raw,
                                            char* __restrict__ xq,
                                            char* __restrict__ w8,
                                            float* __restrict__ sxr) {
  __shared__ float sx[IN_F];               // 16 KB
  __shared__ unsigned short sperm[IN_F];   // 8 KB
  __shared__ float red[4];
  __shared__ int sflag;
  const int b = blockIdx.x;
  const int t = threadIdx.x;

  if (b < M_ROWS) {
    const int m = b;
    const float* xr = x + (size_t)m * IN_F;
#pragma unroll
    for (int u = 0; u < 4; ++u) {
      int idx = (u * 256 + t) * 4;
      *(float4*)&sx[idx] = *(const float4*)&xr[idx];
    }
    if (t < 64) {
      const int* w = (const int*)perm_raw;
      int j = t & 31;
      int lo = w[2 * j], hi = w[2 * j + 1];
      int cond = (hi == 0 && lo >= 0 && lo < IN_F);
      unsigned long long bal = __ballot(cond);
      if (t == 0) sflag = (bal == ~0ull) ? 1 : 0;
    }
    __syncthreads();
    if (sflag) {
      const int4* p4 = (const int4*)perm_raw;  // 16B = 2 int64
#pragma unroll
      for (int u = 0; u < 8; ++u) {
        int idx = u * 256 + t;
        int4 v = p4[idx];
        sperm[2 * idx]     = (unsigned short)v.x;
        sperm[2 * idx + 1] = (unsigned short)v.z;
      }
    } else {
      const int4* p4 = (const int4*)perm_raw;  // 16B = 4 int32
#pragma unroll
      for (int u = 0; u < 4; ++u) {
        int idx = u * 256 + t;
        int4 v = p4[idx];
        sperm[4 * idx]     = (unsigned short)v.x;
        sperm[4 * idx + 1] = (unsigned short)v.y;
        sperm[4 * idx + 2] = (unsigned short)v.z;
        sperm[4 * idx + 3] = (unsigned short)v.w;
      }
    }
    __syncthreads();
    const int jb = t * 16;
    float vals[16];
    float lmax = 0.f;
#pragma unroll
    for (int u = 0; u < 16; ++u) {
      int pj = sperm[jb + u];
      float v = sx[pj];
      vals[u] = v;
      lmax = fmaxf(lmax, fabsf(v));
    }
#pragma unroll
    for (int d = 1; d < 64; d <<= 1)
      lmax = fmaxf(lmax, __shfl_xor(lmax, d, 64));
    if ((t & 63) == 0) red[t >> 6] = lmax;
    __syncthreads();
    float rmax = fmaxf(fmaxf(red[0], red[1]), fmaxf(red[2], red[3]));
    float inv = (rmax > 0.f) ? 127.f / rmax : 0.f;
    if (t == 0) sxr[m] = rmax / 127.f;
    char q[16] __attribute__((aligned(16)));
#pragma unroll
    for (int u = 0; u < 16; ++u)
      q[u] = (char)__float2int_rn(vals[u] * inv);
    *(uint4*)(xq + (size_t)m * IN_F + jb) = *(const uint4*)q;
  } else {
    const int o  = b - M_ROWS;
    const int kb = t * 16;
    const int* wr = w_q + (size_t)o * IN_F + kb;
    int4 w0 = *(const int4*)(wr + 0);
    int4 w1 = *(const int4*)(wr + 4);
    int4 w2 = *(const int4*)(wr + 8);
    int4 w3 = *(const int4*)(wr + 12);
    char q[16] __attribute__((aligned(16)));
    q[0]=(char)w0.x; q[1]=(char)w0.y; q[2]=(char)w0.z; q[3]=(char)w0.w;
    q[4]=(char)w1.x; q[5]=(char)w1.y; q[6]=(char)w1.z; q[7]=(char)w1.w;
    q[8]=(char)w2.x; q[9]=(char)w2.y; q[10]=(char)w2.z; q[11]=(char)w2.w;
    q[12]=(char)w3.x; q[13]=(char)w3.y; q[14]=(char)w3.z; q[15]=(char)w3.w;
    *(uint4*)(w8 + (size_t)o * IN_F + kb) = *(const uint4*)q;
  }
}

// C[m,o] = sxr[m] * sum_g s_w[g,o] * (int8 dot over group g) + bias[o]
//
// R18: cross-tile fragment-read pipelining. Phase model that closes the
// 55us plateau (131Kcyc = 32 x [LDS ~2300 + MFMA ~1300 + rescale ~500]):
// the three phases SERIALIZE because each wave's order is read->wait->MFMA
// ->rescale and barriers align all waves. Fix: issue tile t+1's 16 frag
// ds_reads BEFORE tile t's MFMA cluster -> LDS phase of t+1 hides under
// MFMA+rescale of t. Floor = max(LDS, MFMA) ~= 2400cyc/tile -> ~32us.
// Needs 2 frag sets (fx/fy, +64 VGPR) -> only fits the R0 geometry:
// 4 waves of 64x64, 2 waves/SIMD, VGPR cap 256 via (256,1) (R14: (256,1)
// ->196 no spill; (256,2) spills at a 128 target). Spill traps avoided:
// no lambdas, no array-pointer params, per-row rescale (acci 16 live),
// macros with static indices.
//
// Sync per tile (trace): lgkm(0) [prefetched frags landed; cover = full
// previous COMPUTE] -> barrier [all waves done reading buf p] -> STAGE
// tile t+2 into buf p -> vmcnt(8) [retires tile t+1's 8 DMAs, cover = full
// previous COMPUTE; the 8 just-issued stay in flight] -> barrier [publish
// buf p^1 = tile t+1] -> READF tile t+1 from buf p^1 (issue only) ->
// COMPUTE tile t from regs (no LDS wait). Tail: vmcnt(0) once at t=30.
__global__ __launch_bounds__(256, 1) void gemm_i8(
    const char* __restrict__ A,     // xq  M x K int8
    const char* __restrict__ B,     // w8  N x K int8
    const float* __restrict__ s_w,  // NG x OUT_F
    const float* __restrict__ sxr,  // M
    const float* __restrict__ bias,
    float* __restrict__ C) {
  __shared__ char smem[2][32768];           // per buf: A 16384 | B 16384
  __shared__ unsigned short sws[NG * 128];  // s_w block, bf16

  const int tid  = threadIdx.x;
  const int wave = tid >> 6;
  const int lane = tid & 63;
  const int bm = blockIdx.y << 7;
  const int bn = blockIdx.x << 7;
  const int wm = (wave >> 1) << 6;
  const int wn = (wave & 1) << 6;
  const int lrow = lane & 15;
  const int quad = lane >> 4;
  const int xlo  = lrow & 7;

  // stage s_w block into LDS as bf16
#pragma unroll
  for (int u = 0; u < 16; ++u) {
    int idx = u * 256 + tid;
    int g = idx >> 7, c = idx & 127;
    __hip_bfloat16 h = __float2bfloat16(s_w[(size_t)g * OUT_F + bn + c]);
    sws[idx] = *(unsigned short*)&h;
  }

  // Staging bases (verified XOR geometry, single base + compile-time h):
  // chunk c = h*256 + wave*64 + lane (h=0..3 per operand): row = h*32 +
  // wave*8 + (lane>>3); kc = (lane&7)^(lane>>3); LDS = h*4096 + wave*1024.
  const char* gAb = A + (size_t)(bm + wave * 8 + (lane >> 3)) * IN_F +
                    (((lane & 7) ^ (lane >> 3)) << 4);
  const char* gBb = B + (size_t)(bn + wave * 8 + (lane >> 3)) * IN_F +
                    (((lane & 7) ^ (lane >> 3)) << 4);
  const int lW = wave * 1024;

  // Fragment LDS addressing (loop-invariant): row&7 == xlo for all frag rows.
  const int aBase = (wm + lrow) * 128;
  const int bBase = 16384 + (wn + lrow) * 128;
  const int slot0 = (quad ^ xlo) << 4;
  const int slot1 = ((4 | quad) ^ xlo) << 4;

  f32x4 accf[4][4] = {};
  const v4i zero4 = {0, 0, 0, 0};
  v4i fxA[2][4], fxB[2][4], fyA[2][4], fyB[2][4];

#define STAGE(P, KN)                                                           \
  {                                                                            \
    _Pragma("unroll")                                                          \
    for (int h = 0; h < 4; ++h)                                                \
      async16(gAb + (size_t)h * (32 * IN_F) + (KN), &smem[P][lW + h * 4096]);  \
    _Pragma("unroll")                                                          \
    for (int h = 0; h < 4; ++h)                                                \
      async16(gBb + (size_t)h * (32 * IN_F) + (KN),                            \
              &smem[P][16384 + lW + h * 4096]);                                \
  }

#define READF(F, P)                                                            \
  {                                                                            \
    _Pragma("unroll")                                                          \
    for (int i = 0; i < 4; ++i)                                                \
      F##A[0][i] = *(const v4i*)&smem[P][aBase + i * 2048 + slot0];            \
    _Pragma("unroll")                                                          \
    for (int j = 0; j < 4; ++j)                                                \
      F##B[0][j] = *(const v4i*)&smem[P][bBase + j * 2048 + slot0];            \
    _Pragma("unroll")                                                          \
    for (int i = 0; i < 4; ++i)                                                \
      F##A[1][i] = *(const v4i*)&smem[P][aBase + i * 2048 + slot1];            \
    _Pragma("unroll")                                                          \
    for (int j = 0; j < 4; ++j)                                                \
      F##B[1][j] = *(const v4i*)&smem[P][bBase + j * 2048 + slot1];            \
  }

#define COMPUTE(T, F)                                                          \
  {                                                                            \
    float swv[4];                                                              \
    _Pragma("unroll")                                                          \
    for (int j = 0; j < 4; ++j) {                                              \
      unsigned int u = sws[(T) * 128 + wn + j * 16 + lrow];                    \
      swv[j] = __uint_as_float(u << 16);                                       \
    }                                                                          \
    _Pragma("unroll")                                                          \
    for (int i = 0; i < 4; ++i) {                                              \
      v4i a0, a1, a2, a3;                                                      \
      __builtin_amdgcn_s_setprio(1);                                           \
      a0 = __builtin_amdgcn_mfma_i32_16x16x64_i8(F##A[0][i], F##B[0][0], zero4, 0, 0, 0); \
      a1 = __builtin_amdgcn_mfma_i32_16x16x64_i8(F##A[0][i], F##B[0][1], zero4, 0, 0, 0); \
      a2 = __builtin_amdgcn_mfma_i32_16x16x64_i8(F##A[0][i], F##B[0][2], zero4, 0, 0, 0); \
      a3 = __builtin_amdgcn_mfma_i32_16x16x64_i8(F##A[0][i], F##B[0][3], zero4, 0, 0, 0); \
      a0 = __builtin_amdgcn_mfma_i32_16x16x64_i8(F##A[1][i], F##B[1][0], a0, 0, 0, 0);    \
      a1 = __builtin_amdgcn_mfma_i32_16x16x64_i8(F##A[1][i], F##B[1][1], a1, 0, 0, 0);    \
      a2 = __builtin_amdgcn_mfma_i32_16x16x64_i8(F##A[1][i], F##B[1][2], a2, 0, 0, 0);    \
      a3 = __builtin_amdgcn_mfma_i32_16x16x64_i8(F##A[1][i], F##B[1][3], a3, 0, 0, 0);    \
      __builtin_amdgcn_s_setprio(0);                                           \
      _Pragma("unroll")                                                        \
      for (int r = 0; r < 4; ++r) {                                            \
        accf[i][0][r] += swv[0] * (float)a0[r];                                \
        accf[i][1][r] += swv[1] * (float)a1[r];                                \
        accf[i][2][r] += swv[2] * (float)a2[r];                                \
        accf[i][3][r] += swv[3] * (float)a3[r];                                \
      }                                                                        \
    }                                                                          \
  }

  // prologue: stage tiles 0,1 (16 DMAs); vmcnt(8) retires tile 0's;
  // lgkm(0) publishes sws; then issue tile-0 frag reads (uncovered once).
  STAGE(0, 0);
  STAGE(1, GRP);
  asm volatile("s_waitcnt vmcnt(8) lgkmcnt(0)" ::: "memory");
  __builtin_amdgcn_s_barrier();
  asm volatile("" ::: "memory");
  READF(fx, 0);

#pragma unroll 1
  for (int it = 0; it < 16; ++it) {
    const int t0 = it * 2;
    // ---- even tile t0 (buf0, frags fx) ----
    asm volatile("s_waitcnt lgkmcnt(0)" ::: "memory");  // fx landed
    __builtin_amdgcn_s_barrier();                       // WAR: buf0 free
    asm volatile("" ::: "memory");
    if (it < 15) {
      STAGE(0, (t0 + 2) * GRP);
      asm volatile("s_waitcnt vmcnt(8)" ::: "memory");  // retire tile t0+1
    } else {
      asm volatile("s_waitcnt vmcnt(0)" ::: "memory");  // tail: tile 31
    }
    __builtin_amdgcn_s_barrier();                       // publish buf1
    asm volatile("" ::: "memory");
    READF(fy, 1);                                       // issue tile t0+1
    COMPUTE(t0, fx);                                    // no LDS wait
    // ---- odd tile t0+1 (buf1, frags fy) ----
    asm volatile("s_waitcnt lgkmcnt(0)" ::: "memory");  // fy landed
    __builtin_amdgcn_s_barrier();                       // WAR: buf1 free
    asm volatile("" ::: "memory");
    if (it < 15) {
      STAGE(1, (t0 + 3) * GRP);
      asm volatile("s_waitcnt vmcnt(8)" ::: "memory");  // retire tile t0+2
      __builtin_amdgcn_s_barrier();                     // publish buf0
      asm volatile("" ::: "memory");
      READF(fx, 0);                                     // issue tile t0+2
    }
    COMPUTE(t0 + 1, fy);
  }
#undef STAGE
#undef READF
#undef COMPUTE

  // Epilogue: C/D layout col=lane&15, row=quad*4+reg (dtype-independent).
#pragma unroll
  for (int i = 0; i < 4; ++i) {
    int r0 = bm + wm + i * 16 + quad * 4;
    float sxv[4];
#pragma unroll
    for (int r = 0; r < 4; ++r) sxv[r] = sxr[r0 + r];
#pragma unroll
    for (int j = 0; j < 4; ++j) {
      int col = bn + wn + j * 16 + lrow;
      float bv = bias[col];
#pragma unroll
      for (int r = 0; r < 4; ++r)
        C[(size_t)(r0 + r) * OUT_F + col] = sxv[r] * accf[i][j][r] + bv;
    }
  }
}

// Correct-but-slow fp32 fallback if workspace is too small.
__global__ void naive_fallback(const float* __restrict__ x, const int* __restrict__ w_q,
                               const float* __restrict__ s_w, const void* __restrict__ perm_raw,
                               const float* __restrict__ bias, float* __restrict__ out) {
  int t = blockIdx.x * blockDim.x + threadIdx.x;
  int m = t >> 12;
  int o = t & 4095;
  const int f = g_perm_is64;
  const long long* p64 = (const long long*)perm_raw;
  const int*       p32 = (const int*)perm_raw;
  const float* xr = x + (size_t)m * IN_F;
  const int*   wr = w_q + (size_t)o * IN_F;
  float acc = 0.f;
  for (int g = 0; g < NG; ++g) {
    float part = 0.f;
    for (int k = 0; k < GRP; ++k) {
      int j = g * GRP + k;
      int pj = f ? (int)p64[j] : p32[j];
      part += xr[pj] * (float)wr[j];
    }
    acc += part * s_w[(size_t)g * OUT_F + o];
  }
  out[t] = acc + bias[o];
}

extern "C" void kernel_launch(void* const* d_in, const int* in_sizes, int n_in,
                              void* d_out, int out_size, void* d_ws, size_t ws_size,
                              hipStream_t stream) {
  const float* x    = (const float*)d_in[0];
  const int*   w_q  = (const int*)d_in[1];
  const float* s_w  = (const float*)d_in[2];
  const void*  perm = d_in[3];   // int64 or int32 -- detected on device
  const float* bias = (const float*)d_in[4];
  float* out = (float*)d_out;

  const size_t xq_bytes = (size_t)M_ROWS * IN_F;            // 8 MiB int8
  const size_t w8_bytes = (size_t)OUT_F * IN_F;             // 16 MiB int8
  const size_t sx_bytes = (size_t)M_ROWS * sizeof(float);   // 8 KiB
  const size_t need = xq_bytes + w8_bytes + sx_bytes;

  if (ws_size < need) {
    decode_flag<<<1, 64, 0, stream>>>(perm);
    naive_fallback<<<(M_ROWS * OUT_F) / 256, 256, 0, stream>>>(x, w_q, s_w, perm, bias, out);
    return;
  }

  char*  xq  = (char*)d_ws;
  char*  w8  = (char*)d_ws + xq_bytes;
  float* sxr = (float*)((char*)d_ws + xq_bytes + w8_bytes);

  prep<<<M_ROWS + OUT_F, 256, 0, stream>>>(x, w_q, perm, xq, w8, sxr);

  dim3 grid(OUT_F / 128, M_ROWS / 128);  // 32 x 16 = 512 blocks, 2/CU
  gemm_i8<<<grid, 256, 0, stream>>>(xq, w8, s_w, sxr, bias, out);
}

// Round 11
// 185.171 us; speedup vs baseline: 1.1626x; 1.1626x over previous
//
#include <hip/hip_runtime.h>
#include <hip/hip_bf16.h>
#include <stdint.h>

#define IN_F   4096
#define OUT_F  4096
#define M_ROWS 2048
#define NG     32
#define GRP    128

typedef int   v4i  __attribute__((ext_vector_type(4)));
typedef float f32x4 __attribute__((ext_vector_type(4)));

typedef const void __attribute__((address_space(1))) cv_g;
typedef void       __attribute__((address_space(3))) v_l;

__device__ __forceinline__ void async16(const void* g, void* l) {
  // global -> LDS DMA, 16B/lane; LDS dest = wave-uniform base + lane*16.
  __builtin_amdgcn_global_load_lds((cv_g*)g, (v_l*)l, 16, 0, 0);
}

// perm dtype flag (fallback path only): 1 if int64, 0 if int32.
__device__ int g_perm_is64;

__global__ void decode_flag(const void* __restrict__ perm_raw) {
  if (threadIdx.x == 0 && blockIdx.x == 0) {
    const int* w = (const int*)perm_raw;
    int ok = 1;
    for (int j = 0; j < 32; ++j) {
      int lo = w[2 * j], hi = w[2 * j + 1];
      if (hi != 0 || lo < 0 || lo >= IN_F) { ok = 0; break; }
    }
    g_perm_is64 = ok;
  }
}

// Fused preprocessing, R17 edition (verified -12us vs baseline prep).
// x-path stages perm coalesced (int4 loads, 16B/lane per instruction) into
// an 8KB ushort LDS table once per block, replacing 128B-stride global
// re-reads (64 cache lines per wave instruction, ~8.4M line-requests across
// 2048 blocks). w-path unchanged.
__global__ __launch_bounds__(256) void prep(const float* __restrict__ x,
                                            const int* __restrict__ w_q,
                                            const void* __restrict__ perm_raw,
                                            char* __restrict__ xq,
                                            char* __restrict__ w8,
                                            float* __restrict__ sxr) {
  __shared__ float sx[IN_F];               // 16 KB
  __shared__ unsigned short sperm[IN_F];   // 8 KB
  __shared__ float red[4];
  __shared__ int sflag;
  const int b = blockIdx.x;
  const int t = threadIdx.x;

  if (b < M_ROWS) {
    const int m = b;
    const float* xr = x + (size_t)m * IN_F;
    // phase 0: stage x row (coalesced float4) + detect perm dtype
#pragma unroll
    for (int u = 0; u < 4; ++u) {
      int idx = (u * 256 + t) * 4;
      *(float4*)&sx[idx] = *(const float4*)&xr[idx];
    }
    if (t < 64) {
      const int* w = (const int*)perm_raw;
      int j = t & 31;  // lanes 32..63 duplicate 0..31 -> same ballot bits
      int lo = w[2 * j], hi = w[2 * j + 1];
      // int64 LE values in [0,4096): hi word always 0. int32 perm: w[2j+1]
      // is a perm value, ==0 for at most one j -> ballot never all-ones.
      int cond = (hi == 0 && lo >= 0 && lo < IN_F);
      unsigned long long bal = __ballot(cond);
      if (t == 0) sflag = (bal == ~0ull) ? 1 : 0;
    }
    __syncthreads();
    // phase 1: stage perm coalesced -> ushort LDS table
    if (sflag) {
      const int4* p4 = (const int4*)perm_raw;  // 16B = 2 int64 (lo at .x/.z)
#pragma unroll
      for (int u = 0; u < 8; ++u) {
        int idx = u * 256 + t;
        int4 v = p4[idx];
        sperm[2 * idx]     = (unsigned short)v.x;
        sperm[2 * idx + 1] = (unsigned short)v.z;
      }
    } else {
      const int4* p4 = (const int4*)perm_raw;  // 16B = 4 int32
#pragma unroll
      for (int u = 0; u < 4; ++u) {
        int idx = u * 256 + t;
        int4 v = p4[idx];
        sperm[4 * idx]     = (unsigned short)v.x;
        sperm[4 * idx + 1] = (unsigned short)v.y;
        sperm[4 * idx + 2] = (unsigned short)v.z;
        sperm[4 * idx + 3] = (unsigned short)v.w;
      }
    }
    __syncthreads();
    // phase 2: gather + row-max + quantize
    const int jb = t * 16;
    float vals[16];
    float lmax = 0.f;
#pragma unroll
    for (int u = 0; u < 16; ++u) {
      int pj = sperm[jb + u];
      float v = sx[pj];
      vals[u] = v;
      lmax = fmaxf(lmax, fabsf(v));
    }
#pragma unroll
    for (int d = 1; d < 64; d <<= 1)
      lmax = fmaxf(lmax, __shfl_xor(lmax, d, 64));
    if ((t & 63) == 0) red[t >> 6] = lmax;
    __syncthreads();
    float rmax = fmaxf(fmaxf(red[0], red[1]), fmaxf(red[2], red[3]));
    float inv = (rmax > 0.f) ? 127.f / rmax : 0.f;
    if (t == 0) sxr[m] = rmax / 127.f;
    char q[16] __attribute__((aligned(16)));
#pragma unroll
    for (int u = 0; u < 16; ++u)
      q[u] = (char)__float2int_rn(vals[u] * inv);
    *(uint4*)(xq + (size_t)m * IN_F + jb) = *(const uint4*)q;
  } else {
    // pack weights: one block per output row o; thread t -> 16 consecutive k
    const int o  = b - M_ROWS;
    const int kb = t * 16;
    const int* wr = w_q + (size_t)o * IN_F + kb;
    int4 w0 = *(const int4*)(wr + 0);
    int4 w1 = *(const int4*)(wr + 4);
    int4 w2 = *(const int4*)(wr + 8);
    int4 w3 = *(const int4*)(wr + 12);
    char q[16] __attribute__((aligned(16)));
    q[0]=(char)w0.x; q[1]=(char)w0.y; q[2]=(char)w0.z; q[3]=(char)w0.w;
    q[4]=(char)w1.x; q[5]=(char)w1.y; q[6]=(char)w1.z; q[7]=(char)w1.w;
    q[8]=(char)w2.x; q[9]=(char)w2.y; q[10]=(char)w2.z; q[11]=(char)w2.w;
    q[12]=(char)w3.x; q[13]=(char)w3.y; q[14]=(char)w3.z; q[15]=(char)w3.w;
    *(uint4*)(w8 + (size_t)o * IN_F + kb) = *(const uint4*)q;
  }
}

// C[m,o] = sxr[m] * sum_g s_w[g,o] * (int8 dot over group g) + bias[o]
//
// FINAL gemm = R16/R17 (best verified of the 55us family: 64 VGPR, no
// spill, 32% occupancy). 128x128 tile, BK=128 double-buffer, 2 blocks/CU,
// 512 thr = 8 waves of 32x64, counted-vmcnt barriers. Session evidence:
// this gemm is invariant at 55-56us / MfmaUtil 24% across 2-vs-4 waves/
// SIMD, counted-vs-drain vmcnt, 1-vs-2 blocks/CU, and cross-tile frag
// pipelining; every structural rewrite (reg-resident operands, bigger
// tiles, deeper pipelines) regressed via spills, chain-lengthening, or
// lost co-residency. The residual idle time is this tile-math's issue/
// latency floor at HIP source level.
__global__ __launch_bounds__(512, 4) void gemm_i8(
    const char* __restrict__ A,     // xq  M x K int8
    const char* __restrict__ B,     // w8  N x K int8
    const float* __restrict__ s_w,  // NG x OUT_F
    const float* __restrict__ sxr,  // M
    const float* __restrict__ bias,
    float* __restrict__ C) {
  __shared__ char smem[2][32768];           // per buf: A 16384 | B 16384 bytes
  __shared__ unsigned short sws[NG * 128];  // s_w for this block's 128 cols, bf16

  const int tid  = threadIdx.x;
  const int wave = tid >> 6;
  const int lane = tid & 63;
  const int bm = blockIdx.y << 7;
  const int bn = blockIdx.x << 7;
  const int wm = (wave >> 1) << 5;   // 4 wave-rows of 32
  const int wn = (wave & 1) << 6;    // 2 wave-cols of 64
  const int lrow = lane & 15;
  const int quad = lane >> 4;

  // stage s_w block into LDS as bf16 (keeps the K-loop free of global loads)
#pragma unroll
  for (int u = 0; u < 8; ++u) {
    int idx = u * 512 + tid;               // [g][c], c = local col
    int g = idx >> 7, c = idx & 127;
    __hip_bfloat16 h = __float2bfloat16(s_w[(size_t)g * OUT_F + bn + c]);
    sws[idx] = *(unsigned short*)&h;
  }

  f32x4 accf[2][4] = {};

  // Staging: per buf 2048 chunks of 16B. Round r = h*8+wave (h=0..3) covers
  // chunks c = r*64 + lane. c<1024 -> A (row=c>>3), else B. kc = (c&7)^(row&7).
  const char* gp[4];
  int lofs[4];
#pragma unroll
  for (int h = 0; h < 4; ++h) {
    int c0 = (h * 8 + wave) * 64;
    int c  = c0 + lane;
    if (c < 1024) {
      int row = c >> 3;
      int kc  = (c & 7) ^ (row & 7);
      gp[h]   = A + (size_t)(bm + row) * IN_F + kc * 16;
      lofs[h] = c0 * 16;
    } else {
      int cb  = c - 1024;
      int row = cb >> 3;
      int kc  = (cb & 7) ^ (row & 7);
      gp[h]   = B + (size_t)(bn + row) * IN_F + kc * 16;
      lofs[h] = 16384 + (c0 - 1024) * 16;
    }
  }

  auto stage = [&](int p, int kn) {
#pragma unroll
    for (int h = 0; h < 4; ++h)
      async16(gp[h] + kn, &smem[p][lofs[h]]);
  };

  auto compute = [&](int p, int g) {
    const char* bufA = smem[p];
    const char* bufB = smem[p] + 16384;
    v4i acci[2][4] = {};
#pragma unroll
    for (int s = 0; s < 2; ++s) {
      v4i af[2], bf[4];
#pragma unroll
      for (int i = 0; i < 2; ++i) {
        int row = wm + i * 16 + lrow;
        af[i] = *(const v4i*)&bufA[row * 128 + (((s << 2) + quad) ^ (row & 7)) * 16];
      }
#pragma unroll
      for (int j = 0; j < 4; ++j) {
        int row = wn + j * 16 + lrow;
        bf[j] = *(const v4i*)&bufB[row * 128 + (((s << 2) + quad) ^ (row & 7)) * 16];
      }
#pragma unroll
      for (int i = 0; i < 2; ++i)
#pragma unroll
        for (int j = 0; j < 4; ++j)
          acci[i][j] = __builtin_amdgcn_mfma_i32_16x16x64_i8(af[i], bf[j], acci[i][j], 0, 0, 0);
    }
    // per-group rescale (exact int32 -> f32, scaled by s_w[g, col])
    float swv[4];
#pragma unroll
    for (int j = 0; j < 4; ++j) {
      unsigned int u = sws[g * 128 + wn + j * 16 + lrow];
      swv[j] = __uint_as_float(u << 16);
    }
#pragma unroll
    for (int i = 0; i < 2; ++i)
#pragma unroll
      for (int j = 0; j < 4; ++j)
#pragma unroll
        for (int r = 0; r < 4; ++r)
          accf[i][j][r] += swv[j] * (float)acci[i][j][r];
  };

  // prologue: stage tiles 0 and 1 (4 DMAs each; queue = 8). vmcnt(4)
  // retires exactly tile 0's DMAs; tile 1's stay in flight across the
  // barrier with a full compute phase to land. lgkmcnt(0) publishes sws.
  stage(0, 0);
  stage(1, 128);
  asm volatile("s_waitcnt vmcnt(4) lgkmcnt(0)" ::: "memory");
  __builtin_amdgcn_s_barrier();
  asm volatile("" ::: "memory");

  for (int k0 = 0; k0 < IN_F; k0 += 256) {
    compute(0, k0 >> 7);                       // read buf0 (tile e)
    asm volatile("s_waitcnt lgkmcnt(0)" ::: "memory");
    __builtin_amdgcn_s_barrier();              // WAR: all waves done with buf0
    asm volatile("" ::: "memory");
    if (k0 + 256 < IN_F) {
      stage(0, k0 + 256);                      // tile e+2 -> buf0
      asm volatile("s_waitcnt vmcnt(4)" ::: "memory");  // retire tile e+1 DMAs
    } else {
      asm volatile("s_waitcnt vmcnt(0)" ::: "memory");  // tail: drain tile 31
    }
    __builtin_amdgcn_s_barrier();              // publish buf1
    asm volatile("" ::: "memory");
    compute(1, (k0 >> 7) + 1);                 // read buf1 (tile e+1)
    if (k0 + 256 < IN_F) {
      asm volatile("s_waitcnt lgkmcnt(0)" ::: "memory");
      __builtin_amdgcn_s_barrier();            // WAR: all waves done with buf1
      asm volatile("" ::: "memory");
      stage(1, k0 + 384);                      // tile e+3 -> buf1
      asm volatile("s_waitcnt vmcnt(4)" ::: "memory");  // retire tile e+2 DMAs
      __builtin_amdgcn_s_barrier();            // publish buf0
      asm volatile("" ::: "memory");
    }
  }

  // Epilogue: C/D layout col=lane&15, row=quad*4+reg (dtype-independent,
  // m89/m121-128). Apply per-row x-scale + bias.
#pragma unroll
  for (int i = 0; i < 2; ++i) {
    int r0 = bm + wm + i * 16 + quad * 4;
    float sxv[4];
#pragma unroll
    for (int r = 0; r < 4; ++r) sxv[r] = sxr[r0 + r];  // quad-broadcast loads
#pragma unroll
    for (int j = 0; j < 4; ++j) {
      int col = bn + wn + j * 16 + lrow;
      float bv = bias[col];
#pragma unroll
      for (int r = 0; r < 4; ++r)
        C[(size_t)(r0 + r) * OUT_F + col] = sxv[r] * accf[i][j][r] + bv;
    }
  }
}

// Correct-but-slow fp32 fallback if workspace is too small.
__global__ void naive_fallback(const float* __restrict__ x, const int* __restrict__ w_q,
                               const float* __restrict__ s_w, const void* __restrict__ perm_raw,
                               const float* __restrict__ bias, float* __restrict__ out) {
  int t = blockIdx.x * blockDim.x + threadIdx.x;
  int m = t >> 12;
  int o = t & 4095;
  const int f = g_perm_is64;
  const long long* p64 = (const long long*)perm_raw;
  const int*       p32 = (const int*)perm_raw;
  const float* xr = x + (size_t)m * IN_F;
  const int*   wr = w_q + (size_t)o * IN_F;
  float acc = 0.f;
  for (int g = 0; g < NG; ++g) {
    float part = 0.f;
    for (int k = 0; k < GRP; ++k) {
      int j = g * GRP + k;
      int pj = f ? (int)p64[j] : p32[j];
      part += xr[pj] * (float)wr[j];
    }
    acc += part * s_w[(size_t)g * OUT_F + o];
  }
  out[t] = acc + bias[o];
}

extern "C" void kernel_launch(void* const* d_in, const int* in_sizes, int n_in,
                              void* d_out, int out_size, void* d_ws, size_t ws_size,
                              hipStream_t stream) {
  const float* x    = (const float*)d_in[0];
  const int*   w_q  = (const int*)d_in[1];
  const float* s_w  = (const float*)d_in[2];
  const void*  perm = d_in[3];   // int64 or int32 -- detected on device
  const float* bias = (const float*)d_in[4];
  float* out = (float*)d_out;

  const size_t xq_bytes = (size_t)M_ROWS * IN_F;            // 8 MiB int8
  const size_t w8_bytes = (size_t)OUT_F * IN_F;             // 16 MiB int8
  const size_t sx_bytes = (size_t)M_ROWS * sizeof(float);   // 8 KiB
  const size_t need = xq_bytes + w8_bytes + sx_bytes;

  if (ws_size < need) {
    decode_flag<<<1, 64, 0, stream>>>(perm);
    naive_fallback<<<(M_ROWS * OUT_F) / 256, 256, 0, stream>>>(x, w_q, s_w, perm, bias, out);
    return;
  }

  char*  xq  = (char*)d_ws;
  char*  w8  = (char*)d_ws + xq_bytes;
  float* sxr = (float*)((char*)d_ws + xq_bytes + w8_bytes);

  prep<<<M_ROWS + OUT_F, 256, 0, stream>>>(x, w_q, perm, xq, w8, sxr);

  dim3 grid(OUT_F / 128, M_ROWS / 128);  // 32 x 16 = 512 blocks, 2/CU
  gemm_i8<<<grid, 512, 0, stream>>>(xq, w8, s_w, sxr, bias, out);
}

// Round 12
// 181.332 us; speedup vs baseline: 1.1872x; 1.0212x over previous
//
#include <hip/hip_runtime.h>
#include <hip/hip_bf16.h>
#include <stdint.h>

#define IN_F   4096
#define OUT_F  4096
#define M_ROWS 2048
#define NG     32
#define GRP    128

typedef int   v4i  __attribute__((ext_vector_type(4)));
typedef float f32x4 __attribute__((ext_vector_type(4)));

typedef const void __attribute__((address_space(1))) cv_g;
typedef void       __attribute__((address_space(3))) v_l;

__device__ __forceinline__ void async16(const void* g, void* l) {
  // global -> LDS DMA, 16B/lane; LDS dest = wave-uniform base + lane*16.
  __builtin_amdgcn_global_load_lds((cv_g*)g, (v_l*)l, 16, 0, 0);
}

// perm dtype flag (fallback path only): 1 if int64, 0 if int32.
__device__ int g_perm_is64;

__global__ void decode_flag(const void* __restrict__ perm_raw) {
  if (threadIdx.x == 0 && blockIdx.x == 0) {
    const int* w = (const int*)perm_raw;
    int ok = 1;
    for (int j = 0; j < 32; ++j) {
      int lo = w[2 * j], hi = w[2 * j + 1];
      if (hi != 0 || lo < 0 || lo >= IN_F) { ok = 0; break; }
    }
    g_perm_is64 = ok;
  }
}

// Fused preprocessing, R19 edition. On top of the verified R17 coalesced
// perm staging (-12us): the x-path's 3-sync serialization is cut to 2.
//  - dtype ballot: every wave computes it redundantly in-register (j=t&31
//    gives each wave the identical 32 (lo,hi) pairs -> identical 64-bit
//    ballot -> wave-uniform flag). No LDS flag, no sync, no idle threads.
//  - x-row staging and perm staging issue back-to-back and meet at ONE
//    barrier; perm-load latency hides under the x float4 loads.
// w-path unchanged (pure streaming, BW-floor).
__global__ __launch_bounds__(256) void prep(const float* __restrict__ x,
                                            const int* __restrict__ w_q,
                                            const void* __restrict__ perm_raw,
                                            char* __restrict__ xq,
                                            char* __restrict__ w8,
                                            float* __restrict__ sxr) {
  __shared__ float sx[IN_F];               // 16 KB
  __shared__ unsigned short sperm[IN_F];   // 8 KB
  __shared__ float red[4];
  const int b = blockIdx.x;
  const int t = threadIdx.x;

  if (b < M_ROWS) {
    const int m = b;
    const float* xr = x + (size_t)m * IN_F;
    // dtype ballot, per-wave, no sync: all waves read the same 32 pairs.
    // int64 LE values in [0,4096): hi word always 0. int32 perm: w[2j+1] is
    // a perm value, ==0 for at most one j -> ballot never all-ones.
    const int* w = (const int*)perm_raw;
    {
      int j = t & 31;
      int lo = w[2 * j], hi = w[2 * j + 1];
      int cond = (hi == 0 && lo >= 0 && lo < IN_F);
      unsigned long long bal = __ballot(cond);
      // wave-uniform; stored per-thread in a register
      w = (const int*)(bal == ~0ull ? (const void*)1 : (const void*)0);  // reuse below
    }
    const int f = (w != 0);
    // stage x row (coalesced float4) and perm (coalesced int4) -> one sync
#pragma unroll
    for (int u = 0; u < 4; ++u) {
      int idx = (u * 256 + t) * 4;
      *(float4*)&sx[idx] = *(const float4*)&xr[idx];
    }
    if (f) {
      const int4* p4 = (const int4*)perm_raw;  // 16B = 2 int64 (lo at .x/.z)
#pragma unroll
      for (int u = 0; u < 8; ++u) {
        int idx = u * 256 + t;
        int4 v = p4[idx];
        sperm[2 * idx]     = (unsigned short)v.x;
        sperm[2 * idx + 1] = (unsigned short)v.z;
      }
    } else {
      const int4* p4 = (const int4*)perm_raw;  // 16B = 4 int32
#pragma unroll
      for (int u = 0; u < 4; ++u) {
        int idx = u * 256 + t;
        int4 v = p4[idx];
        sperm[4 * idx]     = (unsigned short)v.x;
        sperm[4 * idx + 1] = (unsigned short)v.y;
        sperm[4 * idx + 2] = (unsigned short)v.z;
        sperm[4 * idx + 3] = (unsigned short)v.w;
      }
    }
    __syncthreads();
    // gather + row-max + quantize
    const int jb = t * 16;
    float vals[16];
    float lmax = 0.f;
#pragma unroll
    for (int u = 0; u < 16; ++u) {
      int pj = sperm[jb + u];
      float v = sx[pj];
      vals[u] = v;
      lmax = fmaxf(lmax, fabsf(v));
    }
#pragma unroll
    for (int d = 1; d < 64; d <<= 1)
      lmax = fmaxf(lmax, __shfl_xor(lmax, d, 64));
    if ((t & 63) == 0) red[t >> 6] = lmax;
    __syncthreads();
    float rmax = fmaxf(fmaxf(red[0], red[1]), fmaxf(red[2], red[3]));
    float inv = (rmax > 0.f) ? 127.f / rmax : 0.f;
    if (t == 0) sxr[m] = rmax / 127.f;
    char q[16] __attribute__((aligned(16)));
#pragma unroll
    for (int u = 0; u < 16; ++u)
      q[u] = (char)__float2int_rn(vals[u] * inv);
    *(uint4*)(xq + (size_t)m * IN_F + jb) = *(const uint4*)q;
  } else {
    // pack weights: one block per output row o; thread t -> 16 consecutive k
    const int o  = b - M_ROWS;
    const int kb = t * 16;
    const int* wr = w_q + (size_t)o * IN_F + kb;
    int4 w0 = *(const int4*)(wr + 0);
    int4 w1 = *(const int4*)(wr + 4);
    int4 w2 = *(const int4*)(wr + 8);
    int4 w3 = *(const int4*)(wr + 12);
    char q[16] __attribute__((aligned(16)));
    q[0]=(char)w0.x; q[1]=(char)w0.y; q[2]=(char)w0.z; q[3]=(char)w0.w;
    q[4]=(char)w1.x; q[5]=(char)w1.y; q[6]=(char)w1.z; q[7]=(char)w1.w;
    q[8]=(char)w2.x; q[9]=(char)w2.y; q[10]=(char)w2.z; q[11]=(char)w2.w;
    q[12]=(char)w3.x; q[13]=(char)w3.y; q[14]=(char)w3.z; q[15]=(char)w3.w;
    *(uint4*)(w8 + (size_t)o * IN_F + kb) = *(const uint4*)q;
  }
}

// C[m,o] = sxr[m] * sum_g s_w[g,o] * (int8 dot over group g) + bias[o]
//
// FINAL gemm = R16/R17 VERBATIM (best verified of the 55us family: 64 VGPR,
// no spill, 32% occupancy). 128x128 tile, BK=128 double-buffer, 2 blocks/CU,
// 512 thr = 8 waves of 32x64, counted-vmcnt barriers. Session evidence:
// invariant at 55-58us / MfmaUtil ~24% across 2-vs-4 waves/SIMD, counted-
// vs-drain vmcnt, 1-vs-2 blocks/CU, cross-tile frag pipelining; every
// structural rewrite regressed (spills / chain-lengthening / co-residency
// loss). Residual idle = this tile-math's issue/latency floor at HIP level.
__global__ __launch_bounds__(512, 4) void gemm_i8(
    const char* __restrict__ A,     // xq  M x K int8
    const char* __restrict__ B,     // w8  N x K int8
    const float* __restrict__ s_w,  // NG x OUT_F
    const float* __restrict__ sxr,  // M
    const float* __restrict__ bias,
    float* __restrict__ C) {
  __shared__ char smem[2][32768];           // per buf: A 16384 | B 16384 bytes
  __shared__ unsigned short sws[NG * 128];  // s_w for this block's 128 cols, bf16

  const int tid  = threadIdx.x;
  const int wave = tid >> 6;
  const int lane = tid & 63;
  const int bm = blockIdx.y << 7;
  const int bn = blockIdx.x << 7;
  const int wm = (wave >> 1) << 5;   // 4 wave-rows of 32
  const int wn = (wave & 1) << 6;    // 2 wave-cols of 64
  const int lrow = lane & 15;
  const int quad = lane >> 4;

  // stage s_w block into LDS as bf16 (keeps the K-loop free of global loads)
#pragma unroll
  for (int u = 0; u < 8; ++u) {
    int idx = u * 512 + tid;               // [g][c], c = local col
    int g = idx >> 7, c = idx & 127;
    __hip_bfloat16 h = __float2bfloat16(s_w[(size_t)g * OUT_F + bn + c]);
    sws[idx] = *(unsigned short*)&h;
  }

  f32x4 accf[2][4] = {};

  // Staging: per buf 2048 chunks of 16B. Round r = h*8+wave (h=0..3) covers
  // chunks c = r*64 + lane. c<1024 -> A (row=c>>3), else B. kc = (c&7)^(row&7).
  const char* gp[4];
  int lofs[4];
#pragma unroll
  for (int h = 0; h < 4; ++h) {
    int c0 = (h * 8 + wave) * 64;
    int c  = c0 + lane;
    if (c < 1024) {
      int row = c >> 3;
      int kc  = (c & 7) ^ (row & 7);
      gp[h]   = A + (size_t)(bm + row) * IN_F + kc * 16;
      lofs[h] = c0 * 16;
    } else {
      int cb  = c - 1024;
      int row = cb >> 3;
      int kc  = (cb & 7) ^ (row & 7);
      gp[h]   = B + (size_t)(bn + row) * IN_F + kc * 16;
      lofs[h] = 16384 + (c0 - 1024) * 16;
    }
  }

  auto stage = [&](int p, int kn) {
#pragma unroll
    for (int h = 0; h < 4; ++h)
      async16(gp[h] + kn, &smem[p][lofs[h]]);
  };

  auto compute = [&](int p, int g) {
    const char* bufA = smem[p];
    const char* bufB = smem[p] + 16384;
    v4i acci[2][4] = {};
#pragma unroll
    for (int s = 0; s < 2; ++s) {
      v4i af[2], bf[4];
#pragma unroll
      for (int i = 0; i < 2; ++i) {
        int row = wm + i * 16 + lrow;
        af[i] = *(const v4i*)&bufA[row * 128 + (((s << 2) + quad) ^ (row & 7)) * 16];
      }
#pragma unroll
      for (int j = 0; j < 4; ++j) {
        int row = wn + j * 16 + lrow;
        bf[j] = *(const v4i*)&bufB[row * 128 + (((s << 2) + quad) ^ (row & 7)) * 16];
      }
#pragma unroll
      for (int i = 0; i < 2; ++i)
#pragma unroll
        for (int j = 0; j < 4; ++j)
          acci[i][j] = __builtin_amdgcn_mfma_i32_16x16x64_i8(af[i], bf[j], acci[i][j], 0, 0, 0);
    }
    // per-group rescale (exact int32 -> f32, scaled by s_w[g, col])
    float swv[4];
#pragma unroll
    for (int j = 0; j < 4; ++j) {
      unsigned int u = sws[g * 128 + wn + j * 16 + lrow];
      swv[j] = __uint_as_float(u << 16);
    }
#pragma unroll
    for (int i = 0; i < 2; ++i)
#pragma unroll
      for (int j = 0; j < 4; ++j)
#pragma unroll
        for (int r = 0; r < 4; ++r)
          accf[i][j][r] += swv[j] * (float)acci[i][j][r];
  };

  // prologue: stage tiles 0 and 1 (4 DMAs each; queue = 8). vmcnt(4)
  // retires exactly tile 0's DMAs; tile 1's stay in flight across the
  // barrier with a full compute phase to land. lgkmcnt(0) publishes sws.
  stage(0, 0);
  stage(1, 128);
  asm volatile("s_waitcnt vmcnt(4) lgkmcnt(0)" ::: "memory");
  __builtin_amdgcn_s_barrier();
  asm volatile("" ::: "memory");

  for (int k0 = 0; k0 < IN_F; k0 += 256) {
    compute(0, k0 >> 7);                       // read buf0 (tile e)
    asm volatile("s_waitcnt lgkmcnt(0)" ::: "memory");
    __builtin_amdgcn_s_barrier();              // WAR: all waves done with buf0
    asm volatile("" ::: "memory");
    if (k0 + 256 < IN_F) {
      stage(0, k0 + 256);                      // tile e+2 -> buf0
      asm volatile("s_waitcnt vmcnt(4)" ::: "memory");  // retire tile e+1 DMAs
    } else {
      asm volatile("s_waitcnt vmcnt(0)" ::: "memory");  // tail: drain tile 31
    }
    __builtin_amdgcn_s_barrier();              // publish buf1
    asm volatile("" ::: "memory");
    compute(1, (k0 >> 7) + 1);                 // read buf1 (tile e+1)
    if (k0 + 256 < IN_F) {
      asm volatile("s_waitcnt lgkmcnt(0)" ::: "memory");
      __builtin_amdgcn_s_barrier();            // WAR: all waves done with buf1
      asm volatile("" ::: "memory");
      stage(1, k0 + 384);                      // tile e+3 -> buf1
      asm volatile("s_waitcnt vmcnt(4)" ::: "memory");  // retire tile e+2 DMAs
      __builtin_amdgcn_s_barrier();            // publish buf0
      asm volatile("" ::: "memory");
    }
  }

  // Epilogue: C/D layout col=lane&15, row=quad*4+reg (dtype-independent,
  // m89/m121-128). Apply per-row x-scale + bias.
#pragma unroll
  for (int i = 0; i < 2; ++i) {
    int r0 = bm + wm + i * 16 + quad * 4;
    float sxv[4];
#pragma unroll
    for (int r = 0; r < 4; ++r) sxv[r] = sxr[r0 + r];  // quad-broadcast loads
#pragma unroll
    for (int j = 0; j < 4; ++j) {
      int col = bn + wn + j * 16 + lrow;
      float bv = bias[col];
#pragma unroll
      for (int r = 0; r < 4; ++r)
        C[(size_t)(r0 + r) * OUT_F + col] = sxv[r] * accf[i][j][r] + bv;
    }
  }
}

// Correct-but-slow fp32 fallback if workspace is too small.
__global__ void naive_fallback(const float* __restrict__ x, const int* __restrict__ w_q,
                               const float* __restrict__ s_w, const void* __restrict__ perm_raw,
                               const float* __restrict__ bias, float* __restrict__ out) {
  int t = blockIdx.x * blockDim.x + threadIdx.x;
  int m = t >> 12;
  int o = t & 4095;
  const int f = g_perm_is64;
  const long long* p64 = (const long long*)perm_raw;
  const int*       p32 = (const int*)perm_raw;
  const float* xr = x + (size_t)m * IN_F;
  const int*   wr = w_q + (size_t)o * IN_F;
  float acc = 0.f;
  for (int g = 0; g < NG; ++g) {
    float part = 0.f;
    for (int k = 0; k < GRP; ++k) {
      int j = g * GRP + k;
      int pj = f ? (int)p64[j] : p32[j];
      part += xr[pj] * (float)wr[j];
    }
    acc += part * s_w[(size_t)g * OUT_F + o];
  }
  out[t] = acc + bias[o];
}

extern "C" void kernel_launch(void* const* d_in, const int* in_sizes, int n_in,
                              void* d_out, int out_size, void* d_ws, size_t ws_size,
                              hipStream_t stream) {
  const float* x    = (const float*)d_in[0];
  const int*   w_q  = (const int*)d_in[1];
  const float* s_w  = (const float*)d_in[2];
  const void*  perm = d_in[3];   // int64 or int32 -- detected on device
  const float* bias = (const float*)d_in[4];
  float* out = (float*)d_out;

  const size_t xq_bytes = (size_t)M_ROWS * IN_F;            // 8 MiB int8
  const size_t w8_bytes = (size_t)OUT_F * IN_F;             // 16 MiB int8
  const size_t sx_bytes = (size_t)M_ROWS * sizeof(float);   // 8 KiB
  const size_t need = xq_bytes + w8_bytes + sx_bytes;

  if (ws_size < need) {
    decode_flag<<<1, 64, 0, stream>>>(perm);
    naive_fallback<<<(M_ROWS * OUT_F) / 256, 256, 0, stream>>>(x, w_q, s_w, perm, bias, out);
    return;
  }

  char*  xq  = (char*)d_ws;
  char*  w8  = (char*)d_ws + xq_bytes;
  float* sxr = (float*)((char*)d_ws + xq_bytes + w8_bytes);

  prep<<<M_ROWS + OUT_F, 256, 0, stream>>>(x, w_q, perm, xq, w8, sxr);

  dim3 grid(OUT_F / 128, M_ROWS / 128);  // 32 x 16 = 512 blocks, 2/CU
  gemm_i8<<<grid, 512, 0, stream>>>(xq, w8, s_w, sxr, bias, out);
}

// Round 13
// 181.123 us; speedup vs baseline: 1.1886x; 1.0012x over previous
//
#include <hip/hip_runtime.h>
#include <hip/hip_bf16.h>
#include <stdint.h>

#define IN_F   4096
#define OUT_F  4096
#define M_ROWS 2048
#define NG     32
#define GRP    128

typedef int   v4i  __attribute__((ext_vector_type(4)));
typedef float f32x4 __attribute__((ext_vector_type(4)));

typedef const void __attribute__((address_space(1))) cv_g;
typedef void       __attribute__((address_space(3))) v_l;

__device__ __forceinline__ void async16(const void* g, void* l) {
  // global -> LDS DMA, 16B/lane; LDS dest = wave-uniform base + lane*16.
  __builtin_amdgcn_global_load_lds((cv_g*)g, (v_l*)l, 16, 0, 0);
}

// perm dtype flag (fallback path only): 1 if int64, 0 if int32.
__device__ int g_perm_is64;

__global__ void decode_flag(const void* __restrict__ perm_raw) {
  if (threadIdx.x == 0 && blockIdx.x == 0) {
    const int* w = (const int*)perm_raw;
    int ok = 1;
    for (int j = 0; j < 32; ++j) {
      int lo = w[2 * j], hi = w[2 * j + 1];
      if (hi != 0 || lo < 0 || lo >= IN_F) { ok = 0; break; }
    }
    g_perm_is64 = ok;
  }
}

// Fused preprocessing (final). Verified wins vs session baseline:
//  - R17: perm staged coalesced (int4 loads) into an 8KB ushort LDS table
//    once per block, replacing 128B-stride global re-reads (-12us).
//  - R19: dtype ballot computed per-wave in-register (all waves read the
//    same 32 pairs -> identical wave-uniform result; no LDS flag, no sync),
//    and x-row + perm staging meet at ONE barrier (3 syncs -> 2, ~-3us).
// w-path: pure streaming int32->int8 pack, HBM-floor-bound.
__global__ __launch_bounds__(256) void prep(const float* __restrict__ x,
                                            const int* __restrict__ w_q,
                                            const void* __restrict__ perm_raw,
                                            char* __restrict__ xq,
                                            char* __restrict__ w8,
                                            float* __restrict__ sxr) {
  __shared__ float sx[IN_F];               // 16 KB
  __shared__ unsigned short sperm[IN_F];   // 8 KB
  __shared__ float red[4];
  const int b = blockIdx.x;
  const int t = threadIdx.x;

  if (b < M_ROWS) {
    const int m = b;
    const float* xr = x + (size_t)m * IN_F;
    // dtype ballot, per-wave, no sync: all waves read the same 32 pairs.
    // int64 LE values in [0,4096): hi word always 0. int32 perm: w[2j+1] is
    // a perm value, ==0 for at most one j -> ballot never all-ones.
    const int* w = (const int*)perm_raw;
    {
      int j = t & 31;
      int lo = w[2 * j], hi = w[2 * j + 1];
      int cond = (hi == 0 && lo >= 0 && lo < IN_F);
      unsigned long long bal = __ballot(cond);
      // wave-uniform; stored per-thread in a register
      w = (const int*)(bal == ~0ull ? (const void*)1 : (const void*)0);
    }
    const int f = (w != 0);
    // stage x row (coalesced float4) and perm (coalesced int4) -> one sync
#pragma unroll
    for (int u = 0; u < 4; ++u) {
      int idx = (u * 256 + t) * 4;
      *(float4*)&sx[idx] = *(const float4*)&xr[idx];
    }
    if (f) {
      const int4* p4 = (const int4*)perm_raw;  // 16B = 2 int64 (lo at .x/.z)
#pragma unroll
      for (int u = 0; u < 8; ++u) {
        int idx = u * 256 + t;
        int4 v = p4[idx];
        sperm[2 * idx]     = (unsigned short)v.x;
        sperm[2 * idx + 1] = (unsigned short)v.z;
      }
    } else {
      const int4* p4 = (const int4*)perm_raw;  // 16B = 4 int32
#pragma unroll
      for (int u = 0; u < 4; ++u) {
        int idx = u * 256 + t;
        int4 v = p4[idx];
        sperm[4 * idx]     = (unsigned short)v.x;
        sperm[4 * idx + 1] = (unsigned short)v.y;
        sperm[4 * idx + 2] = (unsigned short)v.z;
        sperm[4 * idx + 3] = (unsigned short)v.w;
      }
    }
    __syncthreads();
    // gather + row-max + quantize
    const int jb = t * 16;
    float vals[16];
    float lmax = 0.f;
#pragma unroll
    for (int u = 0; u < 16; ++u) {
      int pj = sperm[jb + u];
      float v = sx[pj];
      vals[u] = v;
      lmax = fmaxf(lmax, fabsf(v));
    }
#pragma unroll
    for (int d = 1; d < 64; d <<= 1)
      lmax = fmaxf(lmax, __shfl_xor(lmax, d, 64));
    if ((t & 63) == 0) red[t >> 6] = lmax;
    __syncthreads();
    float rmax = fmaxf(fmaxf(red[0], red[1]), fmaxf(red[2], red[3]));
    float inv = (rmax > 0.f) ? 127.f / rmax : 0.f;
    if (t == 0) sxr[m] = rmax / 127.f;
    char q[16] __attribute__((aligned(16)));
#pragma unroll
    for (int u = 0; u < 16; ++u)
      q[u] = (char)__float2int_rn(vals[u] * inv);
    *(uint4*)(xq + (size_t)m * IN_F + jb) = *(const uint4*)q;
  } else {
    // pack weights: one block per output row o; thread t -> 16 consecutive k
    const int o  = b - M_ROWS;
    const int kb = t * 16;
    const int* wr = w_q + (size_t)o * IN_F + kb;
    int4 w0 = *(const int4*)(wr + 0);
    int4 w1 = *(const int4*)(wr + 4);
    int4 w2 = *(const int4*)(wr + 8);
    int4 w3 = *(const int4*)(wr + 12);
    char q[16] __attribute__((aligned(16)));
    q[0]=(char)w0.x; q[1]=(char)w0.y; q[2]=(char)w0.z; q[3]=(char)w0.w;
    q[4]=(char)w1.x; q[5]=(char)w1.y; q[6]=(char)w1.z; q[7]=(char)w1.w;
    q[8]=(char)w2.x; q[9]=(char)w2.y; q[10]=(char)w2.z; q[11]=(char)w2.w;
    q[12]=(char)w3.x; q[13]=(char)w3.y; q[14]=(char)w3.z; q[15]=(char)w3.w;
    *(uint4*)(w8 + (size_t)o * IN_F + kb) = *(const uint4*)q;
  }
}

// C[m,o] = sxr[m] * sum_g s_w[g,o] * (int8 dot over group g) + bias[o]
//
// FINAL gemm (best verified of the 55us family: 64 VGPR, no spill, 32%
// occupancy). 128x128 tile, BK=128 double-buffer, 2 blocks/CU, 512 thr =
// 8 waves of 32x64, counted-vmcnt barriers. Session evidence: invariant at
// 54-58us / MfmaUtil ~24% across 2-vs-4 waves/SIMD, counted-vs-drain
// vmcnt, 1-vs-2 blocks/CU, cross-tile frag pipelining; every structural
// rewrite regressed (spills / chain-lengthening / co-residency loss).
// Residual idle = this tile-math's issue/latency floor at HIP level.
__global__ __launch_bounds__(512, 4) void gemm_i8(
    const char* __restrict__ A,     // xq  M x K int8
    const char* __restrict__ B,     // w8  N x K int8
    const float* __restrict__ s_w,  // NG x OUT_F
    const float* __restrict__ sxr,  // M
    const float* __restrict__ bias,
    float* __restrict__ C) {
  __shared__ char smem[2][32768];           // per buf: A 16384 | B 16384 bytes
  __shared__ unsigned short sws[NG * 128];  // s_w for this block's 128 cols, bf16

  const int tid  = threadIdx.x;
  const int wave = tid >> 6;
  const int lane = tid & 63;
  const int bm = blockIdx.y << 7;
  const int bn = blockIdx.x << 7;
  const int wm = (wave >> 1) << 5;   // 4 wave-rows of 32
  const int wn = (wave & 1) << 6;    // 2 wave-cols of 64
  const int lrow = lane & 15;
  const int quad = lane >> 4;

  // stage s_w block into LDS as bf16 (keeps the K-loop free of global loads)
#pragma unroll
  for (int u = 0; u < 8; ++u) {
    int idx = u * 512 + tid;               // [g][c], c = local col
    int g = idx >> 7, c = idx & 127;
    __hip_bfloat16 h = __float2bfloat16(s_w[(size_t)g * OUT_F + bn + c]);
    sws[idx] = *(unsigned short*)&h;
  }

  f32x4 accf[2][4] = {};

  // Staging: per buf 2048 chunks of 16B. Round r = h*8+wave (h=0..3) covers
  // chunks c = r*64 + lane. c<1024 -> A (row=c>>3), else B. kc = (c&7)^(row&7).
  const char* gp[4];
  int lofs[4];
#pragma unroll
  for (int h = 0; h < 4; ++h) {
    int c0 = (h * 8 + wave) * 64;
    int c  = c0 + lane;
    if (c < 1024) {
      int row = c >> 3;
      int kc  = (c & 7) ^ (row & 7);
      gp[h]   = A + (size_t)(bm + row) * IN_F + kc * 16;
      lofs[h] = c0 * 16;
    } else {
      int cb  = c - 1024;
      int row = cb >> 3;
      int kc  = (cb & 7) ^ (row & 7);
      gp[h]   = B + (size_t)(bn + row) * IN_F + kc * 16;
      lofs[h] = 16384 + (c0 - 1024) * 16;
    }
  }

  auto stage = [&](int p, int kn) {
#pragma unroll
    for (int h = 0; h < 4; ++h)
      async16(gp[h] + kn, &smem[p][lofs[h]]);
  };

  auto compute = [&](int p, int g) {
    const char* bufA = smem[p];
    const char* bufB = smem[p] + 16384;
    v4i acci[2][4] = {};
#pragma unroll
    for (int s = 0; s < 2; ++s) {
      v4i af[2], bf[4];
#pragma unroll
      for (int i = 0; i < 2; ++i) {
        int row = wm + i * 16 + lrow;
        af[i] = *(const v4i*)&bufA[row * 128 + (((s << 2) + quad) ^ (row & 7)) * 16];
      }
#pragma unroll
      for (int j = 0; j < 4; ++j) {
        int row = wn + j * 16 + lrow;
        bf[j] = *(const v4i*)&bufB[row * 128 + (((s << 2) + quad) ^ (row & 7)) * 16];
      }
#pragma unroll
      for (int i = 0; i < 2; ++i)
#pragma unroll
        for (int j = 0; j < 4; ++j)
          acci[i][j] = __builtin_amdgcn_mfma_i32_16x16x64_i8(af[i], bf[j], acci[i][j], 0, 0, 0);
    }
    // per-group rescale (exact int32 -> f32, scaled by s_w[g, col])
    float swv[4];
#pragma unroll
    for (int j = 0; j < 4; ++j) {
      unsigned int u = sws[g * 128 + wn + j * 16 + lrow];
      swv[j] = __uint_as_float(u << 16);
    }
#pragma unroll
    for (int i = 0; i < 2; ++i)
#pragma unroll
      for (int j = 0; j < 4; ++j)
#pragma unroll
        for (int r = 0; r < 4; ++r)
          accf[i][j][r] += swv[j] * (float)acci[i][j][r];
  };

  // prologue: stage tiles 0 and 1 (4 DMAs each; queue = 8). vmcnt(4)
  // retires exactly tile 0's DMAs; tile 1's stay in flight across the
  // barrier with a full compute phase to land. lgkmcnt(0) publishes sws.
  stage(0, 0);
  stage(1, 128);
  asm volatile("s_waitcnt vmcnt(4) lgkmcnt(0)" ::: "memory");
  __builtin_amdgcn_s_barrier();
  asm volatile("" ::: "memory");

  for (int k0 = 0; k0 < IN_F; k0 += 256) {
    compute(0, k0 >> 7);                       // read buf0 (tile e)
    asm volatile("s_waitcnt lgkmcnt(0)" ::: "memory");
    __builtin_amdgcn_s_barrier();              // WAR: all waves done with buf0
    asm volatile("" ::: "memory");
    if (k0 + 256 < IN_F) {
      stage(0, k0 + 256);                      // tile e+2 -> buf0
      asm volatile("s_waitcnt vmcnt(4)" ::: "memory");  // retire tile e+1 DMAs
    } else {
      asm volatile("s_waitcnt vmcnt(0)" ::: "memory");  // tail: drain tile 31
    }
    __builtin_amdgcn_s_barrier();              // publish buf1
    asm volatile("" ::: "memory");
    compute(1, (k0 >> 7) + 1);                 // read buf1 (tile e+1)
    if (k0 + 256 < IN_F) {
      asm volatile("s_waitcnt lgkmcnt(0)" ::: "memory");
      __builtin_amdgcn_s_barrier();            // WAR: all waves done with buf1
      asm volatile("" ::: "memory");
      stage(1, k0 + 384);                      // tile e+3 -> buf1
      asm volatile("s_waitcnt vmcnt(4)" ::: "memory");  // retire tile e+2 DMAs
      __builtin_amdgcn_s_barrier();            // publish buf0
      asm volatile("" ::: "memory");
    }
  }

  // Epilogue: C/D layout col=lane&15, row=quad*4+reg (dtype-independent,
  // m89/m121-128). Apply per-row x-scale + bias.
#pragma unroll
  for (int i = 0; i < 2; ++i) {
    int r0 = bm + wm + i * 16 + quad * 4;
    float sxv[4];
#pragma unroll
    for (int r = 0; r < 4; ++r) sxv[r] = sxr[r0 + r];  // quad-broadcast loads
#pragma unroll
    for (int j = 0; j < 4; ++j) {
      int col = bn + wn + j * 16 + lrow;
      float bv = bias[col];
#pragma unroll
      for (int r = 0; r < 4; ++r)
        C[(size_t)(r0 + r) * OUT_F + col] = sxv[r] * accf[i][j][r] + bv;
    }
  }
}

// Correct-but-slow fp32 fallback if workspace is too small.
__global__ void naive_fallback(const float* __restrict__ x, const int* __restrict__ w_q,
                               const float* __restrict__ s_w, const void* __restrict__ perm_raw,
                               const float* __restrict__ bias, float* __restrict__ out) {
  int t = blockIdx.x * blockDim.x + threadIdx.x;
  int m = t >> 12;
  int o = t & 4095;
  const int f = g_perm_is64;
  const long long* p64 = (const long long*)perm_raw;
  const int*       p32 = (const int*)perm_raw;
  const float* xr = x + (size_t)m * IN_F;
  const int*   wr = w_q + (size_t)o * IN_F;
  float acc = 0.f;
  for (int g = 0; g < NG; ++g) {
    float part = 0.f;
    for (int k = 0; k < GRP; ++k) {
      int j = g * GRP + k;
      int pj = f ? (int)p64[j] : p32[j];
      part += xr[pj] * (float)wr[j];
    }
    acc += part * s_w[(size_t)g * OUT_F + o];
  }
  out[t] = acc + bias[o];
}

extern "C" void kernel_launch(void* const* d_in, const int* in_sizes, int n_in,
                              void* d_out, int out_size, void* d_ws, size_t ws_size,
                              hipStream_t stream) {
  const float* x    = (const float*)d_in[0];
  const int*   w_q  = (const int*)d_in[1];
  const float* s_w  = (const float*)d_in[2];
  const void*  perm = d_in[3];   // int64 or int32 -- detected on device
  const float* bias = (const float*)d_in[4];
  float* out = (float*)d_out;

  const size_t xq_bytes = (size_t)M_ROWS * IN_F;            // 8 MiB int8
  const size_t w8_bytes = (size_t)OUT_F * IN_F;             // 16 MiB int8
  const size_t sx_bytes = (size_t)M_ROWS * sizeof(float);   // 8 KiB
  const size_t need = xq_bytes + w8_bytes + sx_bytes;

  if (ws_size < need) {
    decode_flag<<<1, 64, 0, stream>>>(perm);
    naive_fallback<<<(M_ROWS * OUT_F) / 256, 256, 0, stream>>>(x, w_q, s_w, perm, bias, out);
    return;
  }

  char*  xq  = (char*)d_ws;
  char*  w8  = (char*)d_ws + xq_bytes;
  float* sxr = (float*)((char*)d_ws + xq_bytes + w8_bytes);

  prep<<<M_ROWS + OUT_F, 256, 0, stream>>>(x, w_q, perm, xq, w8, sxr);

  dim3 grid(OUT_F / 128, M_ROWS / 128);  // 32 x 16 = 512 blocks, 2/CU
  gemm_i8<<<grid, 512, 0, stream>>>(xq, w8, s_w, sxr, bias, out);
}